// Round 6
// baseline (38.027 us; speedup 1.0000x reference)
//
#include <hip/hip_runtime.h>
#include <cfloat>

#define SCOPE 5
#define MASK_MAG 9999.0f
constexpr int F = 256;     // hiddenNoduleNumbers
constexpr int TW = 16;     // t's per wave
constexpr int WAVES = 4;   // waves per block -> block covers 64 t's

// DPP-based wave reduction: 4 VALU DPP-adds (within 16 lanes) + 2 shfl_xor.
template <int CTRL>
__device__ __forceinline__ float dppadd(float x) {
    int v = __builtin_amdgcn_update_dpp(0, __float_as_int(x), CTRL, 0xF, 0xF, true);
    return x + __int_as_float(v);
}
__device__ __forceinline__ float wave_sum(float s) {
    s = dppadd<0xB1>(s);   // quad_perm(1,0,3,2): + lane^1
    s = dppadd<0x4E>(s);   // quad_perm(2,3,0,1): + lane^2
    s = dppadd<0x141>(s);  // row_half_mirror:    + other quad (8-sum)
    s = dppadd<0x140>(s);  // row_mirror:         + other half (16-sum)
    s += __shfl_xor(s, 16, 64);
    s += __shfl_xor(s, 32, 64);
    return s;
}

// ---------------------------------------------------------------------------
// K1: fused sliding-window scores + online-softmax weighted accumulation.
// One wave per 16 t's; 16-slot register ring (rows t0..t0+15, then 4 reused
// slots for rows t0+16..19). Each data row loaded from HBM exactly once.
// Online softmax in groups of 8. Per-block (4-wave) partial combine in LDS.
// ---------------------------------------------------------------------------
__global__ __launch_bounds__(256, 4) void fused_kernel(
    const float* __restrict__ data, const float* __restrict__ W,
    const float* __restrict__ bias, const int* __restrict__ seq,
    float* __restrict__ scores, float* __restrict__ pacc,
    float* __restrict__ pm, float* __restrict__ ps, int T) {
    const int b = blockIdx.y;
    const int tid = threadIdx.x;
    const int lane = tid & 63;
    const int wid = tid >> 6;
    const int lane4 = lane * 4;
    const int t0 = (blockIdx.x * WAVES + wid) * TW;
    const float* __restrict__ dBase = data + (size_t)b * T * F;
    float* __restrict__ sb = scores + (size_t)b * T;
    const float bv = bias[0];
    const int L = seq[b];

    float4 w[SCOPE];
    #pragma unroll
    for (int v = 0; v < SCOPE; ++v)
        w[v] = *(const float4*)(W + v * F + lane4);

    const float4 fz = make_float4(0.f, 0.f, 0.f, 0.f);
    float4 S[16];

#define LOADROW(slot, off) do { \
    const int uu = t0 + (off); \
    S[slot] = (uu < T) ? *(const float4*)(dBase + (size_t)uu * F + lane4) : fz; \
    } while (0)
#define DOT4(a, b) ((a).x*(b).x + (a).y*(b).y + (a).z*(b).z + (a).w*(b).w)

    // prologue: rows t0..t0+15
    #pragma unroll
    for (int k = 0; k < 16; ++k) LOADROW(k, k);

    float m_run = -FLT_MAX, s_run = 0.f;
    float4 acc = fz;
    float sc[8];

    // ---- group A: t = t0..t0+7, dots use slots j..j+4 (<=11) ----
    #pragma unroll
    for (int j = 0; j < 8; ++j) {
        float s = DOT4(S[j], w[0]) + DOT4(S[j+1], w[1]) + DOT4(S[j+2], w[2])
                + DOT4(S[j+3], w[3]) + DOT4(S[j+4], w[4]);
        s = wave_sum(s) + bv;
        const int t = t0 + j;
        if (lane == 0) sb[t] = s;
        sc[j] = fminf(s, (t < L) ? MASK_MAG : -MASK_MAG);
    }
    {   // online update A (rows in slots 0..7)
        float gm = fmaxf(fmaxf(fmaxf(sc[0], sc[1]), fmaxf(sc[2], sc[3])),
                         fmaxf(fmaxf(sc[4], sc[5]), fmaxf(sc[6], sc[7])));
        const float m_new = fmaxf(m_run, gm);
        const float corr = expf(m_run - m_new);
        float psum = 0.f; float4 ga = fz;
        #pragma unroll
        for (int j = 0; j < 8; ++j) {
            const float p = expf(sc[j] - m_new);
            psum += p;
            ga.x += p * S[j].x; ga.y += p * S[j].y;
            ga.z += p * S[j].z; ga.w += p * S[j].w;
        }
        s_run = s_run * corr + psum;
        acc.x = acc.x * corr + ga.x; acc.y = acc.y * corr + ga.y;
        acc.z = acc.z * corr + ga.z; acc.w = acc.w * corr + ga.w;
        m_run = m_new;
    }
    // prefetch rows t0+16..19 into dead slots 0..3
    #pragma unroll
    for (int k = 0; k < 4; ++k) LOADROW(k, 16 + k);

    // ---- group B: t = t0+8..t0+15, dots use slots (8+j..12+j) & 15 ----
    #pragma unroll
    for (int j = 0; j < 8; ++j) {
        float s = DOT4(S[(8+j) & 15], w[0]) + DOT4(S[(9+j) & 15], w[1])
                + DOT4(S[(10+j) & 15], w[2]) + DOT4(S[(11+j) & 15], w[3])
                + DOT4(S[(12+j) & 15], w[4]);
        s = wave_sum(s) + bv;
        const int t = t0 + 8 + j;
        if (lane == 0) sb[t] = s;
        sc[j] = fminf(s, (t < L) ? MASK_MAG : -MASK_MAG);
    }
    {   // online update B (rows in slots 8..15)
        float gm = fmaxf(fmaxf(fmaxf(sc[0], sc[1]), fmaxf(sc[2], sc[3])),
                         fmaxf(fmaxf(sc[4], sc[5]), fmaxf(sc[6], sc[7])));
        const float m_new = fmaxf(m_run, gm);
        const float corr = expf(m_run - m_new);
        float psum = 0.f; float4 ga = fz;
        #pragma unroll
        for (int j = 0; j < 8; ++j) {
            const float p = expf(sc[j] - m_new);
            psum += p;
            ga.x += p * S[8 + j].x; ga.y += p * S[8 + j].y;
            ga.z += p * S[8 + j].z; ga.w += p * S[8 + j].w;
        }
        s_run = s_run * corr + psum;
        acc.x = acc.x * corr + ga.x; acc.y = acc.y * corr + ga.y;
        acc.z = acc.z * corr + ga.z; acc.w = acc.w * corr + ga.w;
        m_run = m_new;
    }
#undef DOT4
#undef LOADROW

    // ---- block-level combine of the 4 waves' (m, s, acc) in LDS ----
    __shared__ float macc[WAVES][F];
    __shared__ float mm[WAVES], ss[WAVES];
    *reinterpret_cast<float4*>(&macc[wid][lane4]) = acc;
    if (lane == 0) { mm[wid] = m_run; ss[wid] = s_run; }
    __syncthreads();

    const float M = fmaxf(fmaxf(mm[0], mm[1]), fmaxf(mm[2], mm[3]));
    float e0 = expf(mm[0] - M), e1 = expf(mm[1] - M);
    float e2 = expf(mm[2] - M), e3 = expf(mm[3] - M);
    const float s_blk = e0 * ss[0] + e1 * ss[1] + e2 * ss[2] + e3 * ss[3];

    const int blk = blockIdx.x;
    const int npb = gridDim.x;                 // partial blocks per batch
    const float ab = e0 * macc[0][tid] + e1 * macc[1][tid]
                   + e2 * macc[2][tid] + e3 * macc[3][tid];
    pacc[((size_t)(b * npb + blk)) * F + tid] = ab;
    if (tid == 0) { pm[b * npb + blk] = M; ps[b * npb + blk] = s_blk; }
}

// ---------------------------------------------------------------------------
// K2: finalize. Grid (B, 9). Every block recomputes global (M, invS) from the
// per-block partials. y==0: reduce pacc -> attentionResult. y=1..8: weights.
// ---------------------------------------------------------------------------
__global__ __launch_bounds__(256) void finalize_kernel(
    const float* __restrict__ scores, const float* __restrict__ pacc,
    const float* __restrict__ pm, const float* __restrict__ ps,
    const int* __restrict__ seq, float* __restrict__ out_res,
    float* __restrict__ out_w, int T, int npb) {
    const int b = blockIdx.x;
    const int part = blockIdx.y;
    const int tid = threadIdx.x;
    __shared__ float MS[2];
    __shared__ float scale[64];   // npb <= 64

    if (tid < 64) {
        const bool v = tid < npb;
        const float m = v ? pm[b * npb + tid] : -FLT_MAX;
        const float s = v ? ps[b * npb + tid] : 0.f;
        float M = m;
        #pragma unroll
        for (int off = 32; off >= 1; off >>= 1) M = fmaxf(M, __shfl_xor(M, off, 64));
        const float e = v ? expf(m - M) : 0.f;
        float se = e * s;
        #pragma unroll
        for (int off = 32; off >= 1; off >>= 1) se += __shfl_xor(se, off, 64);
        scale[tid] = e;
        if (tid == 0) { MS[0] = M; MS[1] = 1.0f / se; }
    }
    __syncthreads();
    const float M = MS[0], invS = MS[1];

    if (part == 0) {
        // attentionResult: thread tid owns feature f = tid
        float o = 0.f;
        for (int i = 0; i < npb; ++i)
            o += scale[i] * pacc[((size_t)(b * npb + i)) * F + tid];
        out_res[(size_t)b * F + tid] = o * invS;
    } else {
        // attentionWeight for t-chunk (part-1)
        const int L = seq[b];
        const int chunk = T / 8;
        const int tbase = (part - 1) * chunk;
        for (int t = tbase + tid; t < tbase + chunk; t += 256) {
            const float raw = scores[(size_t)b * T + t];
            const float msk = fminf(raw, (t < L) ? MASK_MAG : -MASK_MAG);
            out_w[(size_t)b * T + t] = expf(msk - M) * invS;
        }
    }
}

extern "C" void kernel_launch(void* const* d_in, const int* in_sizes, int n_in,
                              void* d_out, int out_size, void* d_ws, size_t ws_size,
                              hipStream_t stream) {
    const float* data = (const float*)d_in[0];
    const int*   seq  = (const int*)d_in[1];
    const float* W    = (const float*)d_in[2];
    const float* bias = (const float*)d_in[3];

    const int B  = in_sizes[1];                 // 32
    const int Fr = in_sizes[2] / SCOPE;         // 256 (== F)
    const int T  = in_sizes[0] / (B * Fr);      // 2048
    (void)Fr;
    const int npb = T / (WAVES * TW);           // 32 block-partials per batch

    float* out_res = (float*)d_out;                      // [B, F]
    float* out_w   = (float*)d_out + (size_t)B * F;      // [B, T]

    float* scores = (float*)d_ws;                        // B*T
    float* pacc   = scores + (size_t)B * T;              // B*npb*F
    float* pm     = pacc + (size_t)B * npb * F;          // B*npb
    float* ps     = pm + (size_t)B * npb;                // B*npb

    dim3 g1(npb, B);                                     // (32, 32)
    fused_kernel<<<g1, 256, 0, stream>>>(data, W, bias, seq, scores, pacc, pm, ps, T);
    dim3 g2(B, 9);
    finalize_kernel<<<g2, 256, 0, stream>>>(scores, pacc, pm, ps, seq, out_res, out_w, T, npb);
}

// Round 7
// 33.508 us; speedup vs baseline: 1.1349x; 1.1349x over previous
//
#include <hip/hip_runtime.h>
#include <cfloat>

#define SCOPE 5
#define MASK_MAG 9999.0f
constexpr int F = 256;     // hiddenNoduleNumbers
constexpr int TW = 32;     // t's per wave
constexpr int WAVES = 4;   // waves per block

// DPP-based partial reduction: quad + row sums (VALU, 1 op each), then 2 shfl.
template <int CTRL>
__device__ __forceinline__ float dppadd(float x) {
    int v = __builtin_amdgcn_update_dpp(0, __float_as_int(x), CTRL, 0xF, 0xF, true);
    return x + __int_as_float(v);
}
__device__ __forceinline__ float wave_sum(float s) {
    s = dppadd<0xB1>(s);   // + lane^1 (quad_perm 1,0,3,2)
    s = dppadd<0x4E>(s);   // + lane^2 (quad_perm 2,3,0,1)
    s = dppadd<0x141>(s);  // + lane^4 (row_half_mirror)
    s = dppadd<0x140>(s);  // + lane^8 (row_mirror) -> 16-lane sums
    s += __shfl_xor(s, 16, 64);
    s += __shfl_xor(s, 32, 64);
    return s;
}

// ---------------------------------------------------------------------------
// K1: fused sliding-window scores + online-softmax weighted accumulation.
// One wave per 32 t's. 24-slot register ring of rows (float4/lane): rows are
// loaded TWO group-periods (~1600 cyc) before first use, exceeding HBM
// latency, so group compute never waits on loads. Each data row is read from
// HBM exactly once (36 rows per 32 t's). Online softmax per group of 8.
// Per-wave partials (m, s, acc[64 floats/lane -> F]) written to ws.
// ---------------------------------------------------------------------------
__global__ __launch_bounds__(256) void fused_kernel(
    const float* __restrict__ data, const float* __restrict__ W,
    const float* __restrict__ bias, const int* __restrict__ seq,
    float* __restrict__ scores, float* __restrict__ pacc,
    float* __restrict__ pm, float* __restrict__ ps, int T) {
    const int b = blockIdx.y;
    const int tid = threadIdx.x;
    const int lane = tid & 63;
    const int wid = tid >> 6;
    const int lane4 = lane * 4;
    const int widx = blockIdx.x * WAVES + wid;
    const int t0 = widx * TW;
    const int npw = T / TW;
    const float* __restrict__ dBase = data + (size_t)b * T * F;
    float* __restrict__ sb = scores + (size_t)b * T;
    const float bv = bias[0];
    const int L = seq[b];

    float4 w[SCOPE];
    #pragma unroll
    for (int v = 0; v < SCOPE; ++v)
        w[v] = *(const float4*)(W + v * F + lane4);

    const float4 fz = make_float4(0.f, 0.f, 0.f, 0.f);
    float4 S[24];

#define SLOT(r) ((r) % 24)
#define LOADROW(slot, off) do { \
    const int uu = t0 + (off); \
    S[slot] = (uu < T) ? *(const float4*)(dBase + (size_t)uu * F + lane4) : fz; \
    } while (0)
#define DOT4(a, b) ((a).x*(b).x + (a).y*(b).y + (a).z*(b).z + (a).w*(b).w)

    // prologue: rows t0 .. t0+23 in flight
    #pragma unroll
    for (int k = 0; k < 24; ++k) LOADROW(k, k);

    float m_run = -FLT_MAX, s_run = 0.f;
    float4 acc = fz;
    float sc[8];

    #pragma unroll
    for (int g = 0; g < 4; ++g) {          // groups A..D, tb = 8g (constants)
        const int tb = g * 8;
        // ---- dots for t = t0+tb .. t0+tb+7 (rows tb..tb+11, all resident)
        #pragma unroll
        for (int j = 0; j < 8; ++j) {
            float s = DOT4(S[SLOT(tb + j)],     w[0])
                    + DOT4(S[SLOT(tb + j + 1)], w[1])
                    + DOT4(S[SLOT(tb + j + 2)], w[2])
                    + DOT4(S[SLOT(tb + j + 3)], w[3])
                    + DOT4(S[SLOT(tb + j + 4)], w[4]);
            s = wave_sum(s) + bv;
            const int t = t0 + tb + j;
            if (lane == 0) sb[t] = s;
            sc[j] = fminf(s, (t < L) ? MASK_MAG : -MASK_MAG);
        }
        // ---- online softmax update (consumes rows tb..tb+7)
        {
            float gm = fmaxf(fmaxf(fmaxf(sc[0], sc[1]), fmaxf(sc[2], sc[3])),
                             fmaxf(fmaxf(sc[4], sc[5]), fmaxf(sc[6], sc[7])));
            const float m_new = fmaxf(m_run, gm);
            const float corr = expf(m_run - m_new);
            float psum = 0.f; float4 ga = fz;
            #pragma unroll
            for (int j = 0; j < 8; ++j) {
                const float p = expf(sc[j] - m_new);
                psum += p;
                const float4 r = S[SLOT(tb + j)];
                ga.x += p * r.x; ga.y += p * r.y;
                ga.z += p * r.z; ga.w += p * r.w;
            }
            s_run = s_run * corr + psum;
            acc.x = acc.x * corr + ga.x; acc.y = acc.y * corr + ga.y;
            acc.z = acc.z * corr + ga.z; acc.w = acc.w * corr + ga.w;
            m_run = m_new;
        }
        // ---- refill freed slots: after A load rows 24..31, after B 32..35
        if (g == 0) {
            #pragma unroll
            for (int k = 0; k < 8; ++k) LOADROW(SLOT(24 + k), 24 + k);
        } else if (g == 1) {
            #pragma unroll
            for (int k = 0; k < 4; ++k) LOADROW(SLOT(32 + k), 32 + k);
        }
    }
#undef DOT4
#undef LOADROW
#undef SLOT

    // per-wave partials
    const int pw = b * npw + widx;
    *reinterpret_cast<float4*>(pacc + (size_t)pw * F + lane4) = acc;
    if (lane == 0) { pm[pw] = m_run; ps[pw] = s_run; }
}

// ---------------------------------------------------------------------------
// K2: finalize. Grid (B, 9). Each block recomputes global (M, invS) from the
// npb=64 wave partials. y==0: reduce pacc -> attentionResult. y=1..8: weights.
// ---------------------------------------------------------------------------
__global__ __launch_bounds__(256) void finalize_kernel(
    const float* __restrict__ scores, const float* __restrict__ pacc,
    const float* __restrict__ pm, const float* __restrict__ ps,
    const int* __restrict__ seq, float* __restrict__ out_res,
    float* __restrict__ out_w, int T, int npb) {
    const int b = blockIdx.x;
    const int part = blockIdx.y;
    const int tid = threadIdx.x;
    __shared__ float MS[2];
    __shared__ float scale[64];   // npb == 64

    if (tid < 64) {
        const float m = pm[b * npb + tid];
        const float s = ps[b * npb + tid];
        float M = m;
        #pragma unroll
        for (int off = 32; off >= 1; off >>= 1) M = fmaxf(M, __shfl_xor(M, off, 64));
        const float e = expf(m - M);
        float se = e * s;
        #pragma unroll
        for (int off = 32; off >= 1; off >>= 1) se += __shfl_xor(se, off, 64);
        scale[tid] = e;
        if (tid == 0) { MS[0] = M; MS[1] = 1.0f / se; }
    }
    __syncthreads();
    const float M = MS[0], invS = MS[1];

    if (part == 0) {
        float o = 0.f;
        for (int i = 0; i < npb; ++i)
            o += scale[i] * pacc[((size_t)(b * npb + i)) * F + tid];
        out_res[(size_t)b * F + tid] = o * invS;
    } else {
        const int L = seq[b];
        const int chunk = T / 8;
        const int tbase = (part - 1) * chunk;
        for (int t = tbase + tid; t < tbase + chunk; t += 256) {
            const float raw = scores[(size_t)b * T + t];
            const float msk = fminf(raw, (t < L) ? MASK_MAG : -MASK_MAG);
            out_w[(size_t)b * T + t] = expf(msk - M) * invS;
        }
    }
}

extern "C" void kernel_launch(void* const* d_in, const int* in_sizes, int n_in,
                              void* d_out, int out_size, void* d_ws, size_t ws_size,
                              hipStream_t stream) {
    const float* data = (const float*)d_in[0];
    const int*   seq  = (const int*)d_in[1];
    const float* W    = (const float*)d_in[2];
    const float* bias = (const float*)d_in[3];

    const int B  = in_sizes[1];                 // 32
    const int Fr = in_sizes[2] / SCOPE;         // 256 (== F)
    const int T  = in_sizes[0] / (B * Fr);      // 2048
    (void)Fr;
    const int npw = T / TW;                     // 64 wave-partials per batch

    float* out_res = (float*)d_out;                      // [B, F]
    float* out_w   = (float*)d_out + (size_t)B * F;      // [B, T]

    float* scores = (float*)d_ws;                        // B*T
    float* pacc   = scores + (size_t)B * T;              // B*npw*F
    float* pm     = pacc + (size_t)B * npw * F;          // B*npw
    float* ps     = pm + (size_t)B * npw;                // B*npw

    dim3 g1(T / (WAVES * TW), B);                        // (16, 32)
    fused_kernel<<<g1, 256, 0, stream>>>(data, W, bias, seq, scores, pacc, pm, ps, T);
    dim3 g2(B, 9);
    finalize_kernel<<<g2, 256, 0, stream>>>(scores, pacc, pm, ps, seq, out_res, out_w, T, npw);
}